// Round 10
// baseline (2394.820 us; speedup 1.0000x reference)
//
#include <hip/hip_runtime.h>
#include <math.h>

// DGM edge sampler, N=8192, DIN=512, DEMB=256, K=16.
// Canonical-f32 pipeline (bit-faithful to the np reference): k-ascending FMA
// GEMMs, explicit __f*_rn at op boundaries, numpy-pairwise row sums.
// Round 10: the round-9 PMC arithmetic showed k_sel is LDS-READ-bound
// (8 waves x 64 b128/chunk = 6144 LDS cyc/CU vs 2048 VALU cyc/SIMD -> 33%
// VALUBusy ~= measured 39%). Fix: R=8 rows/thread (4R=32 FMA per b128),
// A-operands via wave-uniform GLOBAL loads from hbI (L1-contiguous layout),
// B staged with double-buffered global_load_lds (linear LDS, no VGPR cost).

#define NN 8192
#define DI 512
#define DE 256
#define TK 16

typedef float4 f4;

__device__ __forceinline__ void gll16(const float* g, float* l) {
  __builtin_amdgcn_global_load_lds(
      (const __attribute__((address_space(1))) void*)g,
      (__attribute__((address_space(3))) void*)l, 16, 0, 0);
}

// ======== K1: xw = x @ W (K=512, small) — round-9 proven col-split ========
template <int KTOT, bool RELU>
__global__ __launch_bounds__(512) void k_gemm(const float* __restrict__ Amat, int lda,
                                              const float* __restrict__ Bmat,
                                              float* __restrict__ Cout) {
  __shared__ float As[32][36];
  __shared__ float Bs[32][128];
  const int i0 = blockIdx.x * 32;
  const int c0 = blockIdx.y * 128;
  const int tid = threadIdx.x;
  const int rg = tid >> 5;
  const int cq = tid & 31;
  const int r0 = rg * 2;
  float acc[2][4] = {};
  f4 pa;
  f4 pb[2];
  if (tid < 256) pa = *(const f4*)&Amat[(size_t)(i0 + (tid >> 3)) * lda + (tid & 7) * 4];
#pragma unroll
  for (int w = 0; w < 2; ++w) {
    const int lin = tid + 512 * w;
    pb[w] = *(const f4*)&Bmat[(size_t)(lin >> 5) * DE + c0 + (lin & 31) * 4];
  }
  for (int k0 = 0; k0 < KTOT; k0 += 32) {
    __syncthreads();
    if (tid < 256) *(f4*)&As[tid >> 3][(tid & 7) * 4] = pa;
#pragma unroll
    for (int w = 0; w < 2; ++w) {
      const int lin = tid + 512 * w;
      *(f4*)&Bs[lin >> 5][(lin & 31) * 4] = pb[w];
    }
    if (k0 + 32 < KTOT) {
      if (tid < 256)
        pa = *(const f4*)&Amat[(size_t)(i0 + (tid >> 3)) * lda + k0 + 32 + (tid & 7) * 4];
#pragma unroll
      for (int w = 0; w < 2; ++w) {
        const int lin = tid + 512 * w;
        pb[w] = *(const f4*)&Bmat[(size_t)(k0 + 32 + (lin >> 5)) * DE + c0 + (lin & 31) * 4];
      }
    }
    __syncthreads();
#pragma unroll
    for (int k4 = 0; k4 < 8; ++k4) {
      f4 av[2];
#pragma unroll
      for (int u = 0; u < 2; ++u) av[u] = *(const f4*)&As[r0 + u][k4 * 4];
#pragma unroll
      for (int kk = 0; kk < 4; ++kk) {
        f4 b = *(const f4*)&Bs[k4 * 4 + kk][cq * 4];
        const float* bf = (const float*)&b;
#pragma unroll
        for (int u = 0; u < 2; ++u) {
          const float a = ((const float*)&av[u])[kk];
#pragma unroll
          for (int m = 0; m < 4; ++m) acc[u][m] = __fmaf_rn(a, bf[m], acc[u][m]);
        }
      }
    }
  }
#pragma unroll
  for (int u = 0; u < 2; ++u) {
    const int i = i0 + r0 + u;
    f4 o;
    float* of = (float*)&o;
#pragma unroll
    for (int m = 0; m < 4; ++m) of[m] = RELU ? fmaxf(acc[u][m], 0.0f) : acc[u][m];
    *(f4*)&Cout[(size_t)i * DE + c0 + cq * 4] = o;
  }
}

// ======== K2: hb = relu(A @ xw), R=8 rows/thread, gll dbuf staging ========
// block 32 rows x 256 cols, 512 threads: rg=tid>>7 rows rg*8 (uniform),
// ct=tid&127 cols ct*2. A f4 direct from global (uniform); B from LDS b64.
__global__ __launch_bounds__(512) void k_dot8(const float* __restrict__ Amat,
                                              const float* __restrict__ Bmat,
                                              float* __restrict__ Cout) {
  __shared__ float Bs[2][32 * 256];  // 64 KB dbuf
  const int i0 = blockIdx.x * 32;
  const int tid = threadIdx.x;
  const int rg = tid >> 7;
  const int ct = tid & 127;
  const int r0 = rg * 8;
  float acc[8][2] = {};
#pragma unroll
  for (int w = 0; w < 4; ++w) {
    const int lin = tid + 512 * w;
    gll16(&Bmat[(size_t)(lin >> 6) * DE + (lin & 63) * 4], &Bs[0][lin * 4]);
  }
  for (int c = 0; c < 256; ++c) {
    __syncthreads();
    if (c + 1 < 256) {
#pragma unroll
      for (int w = 0; w < 4; ++w) {
        const int lin = tid + 512 * w;
        gll16(&Bmat[(size_t)((c + 1) * 32 + (lin >> 6)) * DE + (lin & 63) * 4],
              &Bs[(c + 1) & 1][lin * 4]);
      }
    }
    const float* bs = &Bs[c & 1][0];
    const int kbase = c * 32;
#pragma unroll 2
    for (int k4 = 0; k4 < 8; ++k4) {
      f4 ar[8];
#pragma unroll
      for (int u = 0; u < 8; ++u)
        ar[u] = *(const f4*)&Amat[(size_t)(i0 + r0 + u) * NN + kbase + k4 * 4];  // uniform
#pragma unroll
      for (int kk = 0; kk < 4; ++kk) {
        float2 b = *(const float2*)&bs[(k4 * 4 + kk) * 256 + ct * 2];
#pragma unroll
        for (int u = 0; u < 8; ++u) {
          const float a = ((const float*)&ar[u])[kk];
          acc[u][0] = __fmaf_rn(a, b.x, acc[u][0]);
          acc[u][1] = __fmaf_rn(a, b.y, acc[u][1]);
        }
      }
    }
  }
#pragma unroll
  for (int u = 0; u < 8; ++u) {
    float2 o;
    o.x = fmaxf(acc[u][0], 0.0f);
    o.y = fmaxf(acc[u][1], 0.0f);
    *(float2*)&Cout[(size_t)(i0 + r0 + u) * DE + ct * 2] = o;
  }
}

// ======== K2b: hbT[k][i] and hbI[i/32][k][i%32] from hb ========
__global__ __launch_bounds__(256) void k_tr(const float* __restrict__ hb,
                                            float* __restrict__ hbT,
                                            float* __restrict__ hbI) {
  __shared__ float t[64][65];
  const int i0 = blockIdx.x * 64;
  const int k0 = blockIdx.y * 64;
  const int tid = threadIdx.x;
#pragma unroll
  for (int l = 0; l < 4; ++l) {
    const int lin = tid + 256 * l;
    const int r = lin >> 4, cqq = lin & 15;
    f4 v = *(const f4*)&hb[(size_t)(i0 + r) * DE + k0 + cqq * 4];
    const float* vf = (const float*)&v;
#pragma unroll
    for (int w = 0; w < 4; ++w) t[r][cqq * 4 + w] = vf[w];
  }
  __syncthreads();
#pragma unroll
  for (int l = 0; l < 4; ++l) {
    const int kk = (tid >> 4) + 16 * l;
    const int iq = tid & 15;
    f4 o;
    float* of = (float*)&o;
#pragma unroll
    for (int w = 0; w < 4; ++w) of[w] = t[iq * 4 + w][kk];
    *(f4*)&hbT[(size_t)(k0 + kk) * NN + i0 + iq * 4] = o;
    const int iabs = i0 + iq * 4;
    *(f4*)&hbI[((size_t)(iabs >> 5) * 256 + (k0 + kk)) * 32 + (iabs & 31)] = o;
  }
}

// ======== K3: sq[i] = sum(h_i*h_i), numpy-pairwise structure ========
__global__ __launch_bounds__(256) void k_sq32(const float* __restrict__ hb,
                                              float* __restrict__ sq) {
  const int row = blockIdx.x * 256 + threadIdx.x;
  const float* h = hb + (size_t)row * DE;
  float half[2];
#pragma unroll
  for (int hx = 0; hx < 2; ++hx) {
    float p[8] = {};
    for (int t = 0; t < 16; ++t) {
      f4 v0 = *(const f4*)&h[hx * 128 + t * 8];
      f4 v1 = *(const f4*)&h[hx * 128 + t * 8 + 4];
      const float* v0f = (const float*)&v0;
      const float* v1f = (const float*)&v1;
#pragma unroll
      for (int m = 0; m < 4; ++m) {
        p[m] = __fadd_rn(p[m], __fmul_rn(v0f[m], v0f[m]));
        p[4 + m] = __fadd_rn(p[4 + m], __fmul_rn(v1f[m], v1f[m]));
      }
    }
    const float t01 = __fadd_rn(p[0], p[1]), t23 = __fadd_rn(p[2], p[3]);
    const float t45 = __fadd_rn(p[4], p[5]), t67 = __fadd_rn(p[6], p[7]);
    half[hx] = __fadd_rn(__fadd_rn(t01, t23), __fadd_rn(t45, t67));
  }
  sq[row] = __fadd_rn(half[0], half[1]);
}

// ======== K4: fused f32 scoring + streaming top-16, R=8 VALU-bound ========
// grid 256, 512 threads, 32 rows x 512-j tiles (16 tiles), LDS 128KB dbuf.
// compute: rg=tid>>7 rows rg*8 (uniform A from hbI), ct=tid&127 cols ct*4.
// scores reuse the dead B-buffer; selectors (all 512): sr=tid>>4, ss=tid&15.
__global__ __launch_bounds__(512) void k_sel(const float* __restrict__ hbI,
                                             const float* __restrict__ hbT,
                                             const float* __restrict__ sqv,
                                             const float* __restrict__ q,
                                             const float* __restrict__ temp,
                                             float* __restrict__ wsV,
                                             int* __restrict__ wsJ) {
  __shared__ float Bs[2][32 * 512];  // 128 KB: B-chunk dbuf / score tile
  const int i0 = blockIdx.x * 32;
  const int tid = threadIdx.x;
  const int rg = tid >> 7;   // wave-uniform
  const int ct = tid & 127;
  const int r0 = rg * 8;
  const int sr = tid >> 4;
  const int ss = tid & 15;

  const float tt = fminf(fmaxf(temp[0], -5.0f), 5.0f);
  const float C = expf(tt);
  float sqi[8];
#pragma unroll
  for (int u = 0; u < 8; ++u) sqi[u] = sqv[i0 + r0 + u];

  float acc[8][4] = {};
  float lv[16];
  int lj[16];
#pragma unroll
  for (int u = 0; u < TK; ++u) { lv[u] = -3.0e38f; lj[u] = 0x7fffffff; }

  const float* abase = hbI + (size_t)(i0 >> 5) * 256 * 32;  // [256][32] L1-hot

  // stage chunk 0 (jt2=0, kc=0)
#pragma unroll
  for (int w = 0; w < 8; ++w) {
    const int lin = tid + 512 * w;
    gll16(&hbT[(size_t)(lin >> 7) * NN + (lin & 127) * 4], &Bs[0][lin * 4]);
  }

  for (int c = 0; c < 128; ++c) {  // chunk: jt2 = c>>3, kc = c&7
    __syncthreads();               // drains prev stage; guards buffer reuse
    if (c + 1 < 128) {
      const int jt2n = (c + 1) >> 3, kcn = (c + 1) & 7;
#pragma unroll
      for (int w = 0; w < 8; ++w) {
        const int lin = tid + 512 * w;
        gll16(&hbT[(size_t)(kcn * 32 + (lin >> 7)) * NN + jt2n * 512 + (lin & 127) * 4],
              &Bs[(c + 1) & 1][lin * 4]);
      }
    }
    const int kc = c & 7;
    const float* bs = &Bs[c & 1][0];
#pragma unroll 2
    for (int k4 = 0; k4 < 8; ++k4) {
#pragma unroll
      for (int kk = 0; kk < 4; ++kk) {
        const int kg = kc * 32 + k4 * 4 + kk;
        f4 a0 = *(const f4*)&abase[(size_t)kg * 32 + r0];      // uniform
        f4 a1 = *(const f4*)&abase[(size_t)kg * 32 + r0 + 4];  // uniform
        f4 b = *(const f4*)&bs[(k4 * 4 + kk) * 512 + ct * 4];  // b128 stride-1
        const float* a0f = (const float*)&a0;
        const float* a1f = (const float*)&a1;
        const float* bf = (const float*)&b;
#pragma unroll
        for (int u = 0; u < 4; ++u)
#pragma unroll
          for (int m = 0; m < 4; ++m)
            acc[u][m] = __fmaf_rn(a0f[u], bf[m], acc[u][m]);
#pragma unroll
        for (int u = 0; u < 4; ++u)
#pragma unroll
          for (int m = 0; m < 4; ++m)
            acc[4 + u][m] = __fmaf_rn(a1f[u], bf[m], acc[4 + u][m]);
      }
    }
    if ((c & 7) == 7) {
      const int j0s = (c >> 3) * 512;
      __syncthreads();  // all waves done reading buf[c&1] -> reuse as scores
      float* sc = &Bs[c & 1][0];
      f4 sqj = *(const f4*)&sqv[j0s + ct * 4];
      const float* sqjf = (const float*)&sqj;
#pragma unroll
      for (int u = 0; u < 8; ++u) {
        f4 qv = *(const f4*)&q[(size_t)(i0 + r0 + u) * NN + j0s + ct * 4];
        const float* qvf = (const float*)&qv;
        f4 sv;
        float* svf = (float*)&sv;
#pragma unroll
        for (int e = 0; e < 4; ++e) {
          const float t1 = __fadd_rn(sqi[u], sqjf[e]);
          float D = __fsub_rn(t1, __fmul_rn(2.0f, acc[u][e]));
          D = fmaxf(D, 0.0f);
          const float lg = __fmul_rn(D, C);
          const float p = __fadd_rn(qvf[e], 1e-8f);
          const float uu = logf(p);
          const float nv = logf(-uu);
          svf[e] = __fsub_rn(nv, lg);
          acc[u][e] = 0.0f;
        }
        *(f4*)&sc[(r0 + u) * 512 + ct * 4] = sv;
      }
      __syncthreads();  // scores ready
      // selection: ascending j (j = j0s + c2*16 + ss), strict > keeps lower j
      for (int c2 = 0; c2 < 32; ++c2) {
        const float v = sc[sr * 512 + c2 * 16 + ss];
        if (v > lv[15]) {
          float cv = v;
          int cj = j0s + c2 * 16 + ss;
#pragma unroll
          for (int u = 0; u < TK; ++u) {
            const bool take = (cv > lv[u]);
            const float nv2 = take ? cv : lv[u];
            const int nj2 = take ? cj : lj[u];
            cv = take ? lv[u] : cv;
            cj = take ? lj[u] : cj;
            lv[u] = nv2;
            lj[u] = nj2;
          }
        }
      }
      // next iter's top barrier protects score buffer vs restaging
    }
  }

  // dump per-selector sorted lists (16 per row)
  const size_t base = ((size_t)(i0 + sr) * 16 + ss) * (size_t)TK;
#pragma unroll
  for (int u = 0; u < TK; ++u) {
    wsV[base + u] = lv[u];
    wsJ[base + u] = lj[u];
  }
}

// ======== K5: exact 16-way cursor merge per row ========
__global__ __launch_bounds__(256) void k_merge(const float* __restrict__ wsV,
                                               const int* __restrict__ wsJ,
                                               float* __restrict__ out) {
  const int r = blockIdx.x * 256 + threadIdx.x;
  int cur[16];
#pragma unroll
  for (int l = 0; l < 16; ++l) cur[l] = 0;
  float* E0 = out + (size_t)NN * DE;
  float* E1 = E0 + (size_t)NN * TK;
  float* LP = E1 + (size_t)NN * TK;
  for (int it = 0; it < TK; ++it) {
    float bv = -3.0e38f;
    int bj = 0x7fffffff, bl = 0;
    for (int l = 0; l < 16; ++l) {
      const int c = cur[l];
      if (c < TK) {
        const size_t base = ((size_t)r * 16 + l) * (size_t)TK;
        const float v = wsV[base + c];
        const int j = wsJ[base + c];
        if (v > bv || (v == bv && j < bj)) { bv = v; bj = j; bl = l; }
      }
    }
    cur[bl]++;
    E0[(size_t)r * TK + it] = (float)bj;
    E1[(size_t)r * TK + it] = (float)r;
    LP[(size_t)r * TK + it] = bv;
  }
}

extern "C" void kernel_launch(void* const* d_in, const int* in_sizes, int n_in,
                              void* d_out, int out_size, void* d_ws, size_t ws_size,
                              hipStream_t stream) {
  const float* x = (const float*)d_in[0];
  const float* A = (const float*)d_in[1];
  const float* W = (const float*)d_in[2];
  const float* temp = (const float*)d_in[3];
  const float* q = (const float*)d_in[4];
  float* out = (float*)d_out;

  char* ws = (char*)d_ws;
  float* xw  = (float*)(ws);             //  8,388,608 B
  float* sq  = (float*)(ws + 8388608);   //     32,768 B
  float* hbT = (float*)(ws + 8421376);   //  8,388,608 B  [256][8192]
  float* hbI = (float*)(ws + 16809984);  //  8,388,608 B  [256][256][32]
  float* wsV = (float*)(ws + 25198592);  //  8,388,608 B  [8192][16][16]
  int*   wsJ = (int*)  (ws + 33587200);  //  8,388,608 B

  float* hb = out;  // [N, DE] f32 output region holds h

  hipLaunchKernelGGL((k_gemm<DI, false>), dim3(NN / 32, 2), dim3(512), 0, stream, x, DI, W, xw);
  hipLaunchKernelGGL(k_dot8, dim3(NN / 32), dim3(512), 0, stream, A, xw, hb);
  hipLaunchKernelGGL(k_tr, dim3(NN / 64, DE / 64), dim3(256), 0, stream, hb, hbT, hbI);
  hipLaunchKernelGGL(k_sq32, dim3(NN / 256), dim3(256), 0, stream, hb, sq);
  hipLaunchKernelGGL(k_sel, dim3(NN / 32), dim3(512), 0, stream, hbI, hbT, sq, q, temp, wsV, wsJ);
  hipLaunchKernelGGL(k_merge, dim3(NN / 256), dim3(256), 0, stream, wsV, wsJ, out);
}

// Round 11
// 1921.329 us; speedup vs baseline: 1.2464x; 1.2464x over previous
//
#include <hip/hip_runtime.h>
#include <math.h>

// DGM edge sampler, N=8192, DIN=512, DEMB=256, K=16.
// Canonical-f32 pipeline (bit-faithful to the np reference): k-ascending FMA
// GEMMs, explicit __f*_rn at op boundaries, numpy-pairwise row sums.
// Round 11: k_dot8's wave-uniform GLOBAL A-loads were latency-bound (streamed
// 1MB window, never cache-hot, 16B/instr in flight -> VALUBusy 30%). Fix:
// A staged via coalesced global_load_lds (1KB/instr), read back as LDS
// broadcasts. Unified k_tile template replaces k_gemm + k_dot8.

#define NN 8192
#define DI 512
#define DE 256
#define TK 16

typedef float4 f4;

__device__ __forceinline__ void gll16(const float* g, float* l) {
  __builtin_amdgcn_global_load_lds(
      (const __attribute__((address_space(1))) void*)g,
      (__attribute__((address_space(3))) void*)l, 16, 0, 0);
}

// ======== K1/K2: C = [relu](Amat @ Bmat[KTOT][256]) ========
// block 32 rows x 256 cols, 512 threads; thread: 8 rows x 2 cols.
// A: LDS row-major [32][32] dbuf via gll16, read as wave-uniform b128 bcast.
// B: LDS [k][col] dbuf via gll16, read as stride-1 b64 (2-way, free).
template <int KTOT, bool RELU>
__global__ __launch_bounds__(512) void k_tile(const float* __restrict__ Amat, int lda,
                                              const float* __restrict__ Bmat,
                                              float* __restrict__ Cout) {
  __shared__ float As[2][32 * 32];   // 8 KB dbuf
  __shared__ float Bs[2][32 * 256];  // 64 KB dbuf
  const int i0 = blockIdx.x * 32;
  const int tid = threadIdx.x;
  const int rg = tid >> 7;   // wave-uniform, 0..3
  const int ct = tid & 127;  // cols ct*2, ct*2+1
  const int r0 = rg * 8;
  constexpr int NC = KTOT / 32;
  float acc[8][2] = {};

  // stage chunk 0
  if (tid < 256)
    gll16(&Amat[(size_t)(i0 + (tid >> 3)) * lda + (tid & 7) * 4], &As[0][tid * 4]);
#pragma unroll
  for (int w = 0; w < 4; ++w) {
    const int lin = tid + 512 * w;
    gll16(&Bmat[(size_t)(lin >> 6) * DE + (lin & 63) * 4], &Bs[0][lin * 4]);
  }

  for (int c = 0; c < NC; ++c) {
    __syncthreads();  // drains stage of chunk c; prev compute done
    if (c + 1 < NC) {
      const int kb = (c + 1) * 32;
      if (tid < 256)
        gll16(&Amat[(size_t)(i0 + (tid >> 3)) * lda + kb + (tid & 7) * 4],
              &As[(c + 1) & 1][tid * 4]);
#pragma unroll
      for (int w = 0; w < 4; ++w) {
        const int lin = tid + 512 * w;
        gll16(&Bmat[(size_t)(kb + (lin >> 6)) * DE + (lin & 63) * 4],
              &Bs[(c + 1) & 1][lin * 4]);
      }
    }
    const float* as = &As[c & 1][0];
    const float* bs = &Bs[c & 1][0];
#pragma unroll 2
    for (int k4 = 0; k4 < 8; ++k4) {
      f4 a[8];
#pragma unroll
      for (int u = 0; u < 8; ++u)
        a[u] = *(const f4*)&as[(r0 + u) * 32 + k4 * 4];  // uniform bcast
#pragma unroll
      for (int kk = 0; kk < 4; ++kk) {  // k ascending
        float2 b = *(const float2*)&bs[(k4 * 4 + kk) * 256 + ct * 2];
#pragma unroll
        for (int u = 0; u < 8; ++u) {
          const float av = ((const float*)&a[u])[kk];
          acc[u][0] = __fmaf_rn(av, b.x, acc[u][0]);
          acc[u][1] = __fmaf_rn(av, b.y, acc[u][1]);
        }
      }
    }
  }
#pragma unroll
  for (int u = 0; u < 8; ++u) {
    float2 o;
    o.x = RELU ? fmaxf(acc[u][0], 0.0f) : acc[u][0];
    o.y = RELU ? fmaxf(acc[u][1], 0.0f) : acc[u][1];
    *(float2*)&Cout[(size_t)(i0 + r0 + u) * DE + ct * 2] = o;
  }
}

// ======== K2b: hbT[k][i] and hbI[i/32][k][i%32] from hb ========
__global__ __launch_bounds__(256) void k_tr(const float* __restrict__ hb,
                                            float* __restrict__ hbT,
                                            float* __restrict__ hbI) {
  __shared__ float t[64][65];
  const int i0 = blockIdx.x * 64;
  const int k0 = blockIdx.y * 64;
  const int tid = threadIdx.x;
#pragma unroll
  for (int l = 0; l < 4; ++l) {
    const int lin = tid + 256 * l;
    const int r = lin >> 4, cqq = lin & 15;
    f4 v = *(const f4*)&hb[(size_t)(i0 + r) * DE + k0 + cqq * 4];
    const float* vf = (const float*)&v;
#pragma unroll
    for (int w = 0; w < 4; ++w) t[r][cqq * 4 + w] = vf[w];
  }
  __syncthreads();
#pragma unroll
  for (int l = 0; l < 4; ++l) {
    const int kk = (tid >> 4) + 16 * l;
    const int iq = tid & 15;
    f4 o;
    float* of = (float*)&o;
#pragma unroll
    for (int w = 0; w < 4; ++w) of[w] = t[iq * 4 + w][kk];
    *(f4*)&hbT[(size_t)(k0 + kk) * NN + i0 + iq * 4] = o;
    const int iabs = i0 + iq * 4;
    *(f4*)&hbI[((size_t)(iabs >> 5) * 256 + (k0 + kk)) * 32 + (iabs & 31)] = o;
  }
}

// ======== K3: sq[i] = sum(h_i*h_i), numpy-pairwise structure ========
__global__ __launch_bounds__(256) void k_sq32(const float* __restrict__ hb,
                                              float* __restrict__ sq) {
  const int row = blockIdx.x * 256 + threadIdx.x;
  const float* h = hb + (size_t)row * DE;
  float half[2];
#pragma unroll
  for (int hx = 0; hx < 2; ++hx) {
    float p[8] = {};
    for (int t = 0; t < 16; ++t) {
      f4 v0 = *(const f4*)&h[hx * 128 + t * 8];
      f4 v1 = *(const f4*)&h[hx * 128 + t * 8 + 4];
      const float* v0f = (const float*)&v0;
      const float* v1f = (const float*)&v1;
#pragma unroll
      for (int m = 0; m < 4; ++m) {
        p[m] = __fadd_rn(p[m], __fmul_rn(v0f[m], v0f[m]));
        p[4 + m] = __fadd_rn(p[4 + m], __fmul_rn(v1f[m], v1f[m]));
      }
    }
    const float t01 = __fadd_rn(p[0], p[1]), t23 = __fadd_rn(p[2], p[3]);
    const float t45 = __fadd_rn(p[4], p[5]), t67 = __fadd_rn(p[6], p[7]);
    half[hx] = __fadd_rn(__fadd_rn(t01, t23), __fadd_rn(t45, t67));
  }
  sq[row] = __fadd_rn(half[0], half[1]);
}

// ======== K4: fused f32 scoring + streaming top-16 (round-10 proven) ========
__global__ __launch_bounds__(512) void k_sel(const float* __restrict__ hbI,
                                             const float* __restrict__ hbT,
                                             const float* __restrict__ sqv,
                                             const float* __restrict__ q,
                                             const float* __restrict__ temp,
                                             float* __restrict__ wsV,
                                             int* __restrict__ wsJ) {
  __shared__ float Bs[2][32 * 512];  // 128 KB: B-chunk dbuf / score tile
  const int i0 = blockIdx.x * 32;
  const int tid = threadIdx.x;
  const int rg = tid >> 7;   // wave-uniform
  const int ct = tid & 127;
  const int r0 = rg * 8;
  const int sr = tid >> 4;
  const int ss = tid & 15;

  const float tt = fminf(fmaxf(temp[0], -5.0f), 5.0f);
  const float C = expf(tt);
  float sqi[8];
#pragma unroll
  for (int u = 0; u < 8; ++u) sqi[u] = sqv[i0 + r0 + u];

  float acc[8][4] = {};
  float lv[16];
  int lj[16];
#pragma unroll
  for (int u = 0; u < TK; ++u) { lv[u] = -3.0e38f; lj[u] = 0x7fffffff; }

  const float* abase = hbI + (size_t)(i0 >> 5) * 256 * 32;  // [256][32] L1-hot

#pragma unroll
  for (int w = 0; w < 8; ++w) {
    const int lin = tid + 512 * w;
    gll16(&hbT[(size_t)(lin >> 7) * NN + (lin & 127) * 4], &Bs[0][lin * 4]);
  }

  for (int c = 0; c < 128; ++c) {  // chunk: jt2 = c>>3, kc = c&7
    __syncthreads();
    if (c + 1 < 128) {
      const int jt2n = (c + 1) >> 3, kcn = (c + 1) & 7;
#pragma unroll
      for (int w = 0; w < 8; ++w) {
        const int lin = tid + 512 * w;
        gll16(&hbT[(size_t)(kcn * 32 + (lin >> 7)) * NN + jt2n * 512 + (lin & 127) * 4],
              &Bs[(c + 1) & 1][lin * 4]);
      }
    }
    const int kc = c & 7;
    const float* bs = &Bs[c & 1][0];
#pragma unroll 2
    for (int k4 = 0; k4 < 8; ++k4) {
#pragma unroll
      for (int kk = 0; kk < 4; ++kk) {
        const int kg = kc * 32 + k4 * 4 + kk;
        f4 a0 = *(const f4*)&abase[(size_t)kg * 32 + r0];
        f4 a1 = *(const f4*)&abase[(size_t)kg * 32 + r0 + 4];
        f4 b = *(const f4*)&bs[(k4 * 4 + kk) * 512 + ct * 4];
        const float* a0f = (const float*)&a0;
        const float* a1f = (const float*)&a1;
        const float* bf = (const float*)&b;
#pragma unroll
        for (int u = 0; u < 4; ++u)
#pragma unroll
          for (int m = 0; m < 4; ++m)
            acc[u][m] = __fmaf_rn(a0f[u], bf[m], acc[u][m]);
#pragma unroll
        for (int u = 0; u < 4; ++u)
#pragma unroll
          for (int m = 0; m < 4; ++m)
            acc[4 + u][m] = __fmaf_rn(a1f[u], bf[m], acc[4 + u][m]);
      }
    }
    if ((c & 7) == 7) {
      const int j0s = (c >> 3) * 512;
      __syncthreads();
      float* sc = &Bs[c & 1][0];
      f4 sqj = *(const f4*)&sqv[j0s + ct * 4];
      const float* sqjf = (const float*)&sqj;
#pragma unroll
      for (int u = 0; u < 8; ++u) {
        f4 qv = *(const f4*)&q[(size_t)(i0 + r0 + u) * NN + j0s + ct * 4];
        const float* qvf = (const float*)&qv;
        f4 sv;
        float* svf = (float*)&sv;
#pragma unroll
        for (int e = 0; e < 4; ++e) {
          const float t1 = __fadd_rn(sqi[u], sqjf[e]);
          float D = __fsub_rn(t1, __fmul_rn(2.0f, acc[u][e]));
          D = fmaxf(D, 0.0f);
          const float lg = __fmul_rn(D, C);
          const float p = __fadd_rn(qvf[e], 1e-8f);
          const float uu = logf(p);
          const float nv = logf(-uu);
          svf[e] = __fsub_rn(nv, lg);
          acc[u][e] = 0.0f;
        }
        *(f4*)&sc[(r0 + u) * 512 + ct * 4] = sv;
      }
      __syncthreads();
      for (int c2 = 0; c2 < 32; ++c2) {
        const float v = sc[sr * 512 + c2 * 16 + ss];
        if (v > lv[15]) {
          float cv = v;
          int cj = j0s + c2 * 16 + ss;
#pragma unroll
          for (int u = 0; u < TK; ++u) {
            const bool take = (cv > lv[u]);
            const float nv2 = take ? cv : lv[u];
            const int nj2 = take ? cj : lj[u];
            cv = take ? lv[u] : cv;
            cj = take ? lj[u] : cj;
            lv[u] = nv2;
            lj[u] = nj2;
          }
        }
      }
    }
  }

  const size_t base = ((size_t)(i0 + sr) * 16 + ss) * (size_t)TK;
#pragma unroll
  for (int u = 0; u < TK; ++u) {
    wsV[base + u] = lv[u];
    wsJ[base + u] = lj[u];
  }
}

// ======== K5: exact 16-way cursor merge per row ========
__global__ __launch_bounds__(256) void k_merge(const float* __restrict__ wsV,
                                               const int* __restrict__ wsJ,
                                               float* __restrict__ out) {
  const int r = blockIdx.x * 256 + threadIdx.x;
  int cur[16];
#pragma unroll
  for (int l = 0; l < 16; ++l) cur[l] = 0;
  float* E0 = out + (size_t)NN * DE;
  float* E1 = E0 + (size_t)NN * TK;
  float* LP = E1 + (size_t)NN * TK;
  for (int it = 0; it < TK; ++it) {
    float bv = -3.0e38f;
    int bj = 0x7fffffff, bl = 0;
    for (int l = 0; l < 16; ++l) {
      const int c = cur[l];
      if (c < TK) {
        const size_t base = ((size_t)r * 16 + l) * (size_t)TK;
        const float v = wsV[base + c];
        const int j = wsJ[base + c];
        if (v > bv || (v == bv && j < bj)) { bv = v; bj = j; bl = l; }
      }
    }
    cur[bl]++;
    E0[(size_t)r * TK + it] = (float)bj;
    E1[(size_t)r * TK + it] = (float)r;
    LP[(size_t)r * TK + it] = bv;
  }
}

extern "C" void kernel_launch(void* const* d_in, const int* in_sizes, int n_in,
                              void* d_out, int out_size, void* d_ws, size_t ws_size,
                              hipStream_t stream) {
  const float* x = (const float*)d_in[0];
  const float* A = (const float*)d_in[1];
  const float* W = (const float*)d_in[2];
  const float* temp = (const float*)d_in[3];
  const float* q = (const float*)d_in[4];
  float* out = (float*)d_out;

  char* ws = (char*)d_ws;
  float* xw  = (float*)(ws);             //  8,388,608 B
  float* sq  = (float*)(ws + 8388608);   //     32,768 B
  float* hbT = (float*)(ws + 8421376);   //  8,388,608 B  [256][8192]
  float* hbI = (float*)(ws + 16809984);  //  8,388,608 B  [256][256][32]
  float* wsV = (float*)(ws + 25198592);  //  8,388,608 B  [8192][16][16]
  int*   wsJ = (int*)  (ws + 33587200);  //  8,388,608 B

  float* hb = out;  // [N, DE] f32 output region holds h

  hipLaunchKernelGGL((k_tile<DI, false>), dim3(NN / 32), dim3(512), 0, stream, x, DI, W, xw);
  hipLaunchKernelGGL((k_tile<NN, true>), dim3(NN / 32), dim3(512), 0, stream, A, NN, xw, hb);
  hipLaunchKernelGGL(k_tr, dim3(NN / 64, DE / 64), dim3(256), 0, stream, hb, hbT, hbI);
  hipLaunchKernelGGL(k_sq32, dim3(NN / 256), dim3(256), 0, stream, hb, sq);
  hipLaunchKernelGGL(k_sel, dim3(NN / 32), dim3(512), 0, stream, hbI, hbT, sq, q, temp, wsV, wsJ);
  hipLaunchKernelGGL(k_merge, dim3(NN / 256), dim3(256), 0, stream, wsV, wsJ, out);
}

// Round 12
// 1624.604 us; speedup vs baseline: 1.4741x; 1.1826x over previous
//
#include <hip/hip_runtime.h>
#include <math.h>

// DGM edge sampler, N=8192, DIN=512, DEMB=256, K=16.
// Canonical-f32 pipeline for h and all REFINED scores (bit-faithful to the
// np reference). Round 12: the O(N^2*D) score GEMM moves to bf16 MFMA
// SCREENING (error bound ~0.002 on scores); ~17 candidates/row are then
// re-scored with the exact canonical f32 chain and exact top-16 selected.

#define NN 8192
#define DI 512
#define DE 256
#define TK 16

typedef float4 f4;
typedef __attribute__((ext_vector_type(8))) short short8v;   // 8 bf16
typedef __attribute__((ext_vector_type(4))) float f32x4;
typedef unsigned short u16;
typedef unsigned int u32;

__device__ __forceinline__ void gll16b(const void* g, void* l) {
  __builtin_amdgcn_global_load_lds(
      (const __attribute__((address_space(1))) void*)g,
      (__attribute__((address_space(3))) void*)l, 16, 0, 0);
}

__device__ __forceinline__ u16 f2bf(float f) {  // RNE f32->bf16
  u32 u = __float_as_uint(f);
  return (u16)((u + 0x7FFFu + ((u >> 16) & 1u)) >> 16);
}

// ======== K1/K2: C = [relu](Amat @ Bmat[KTOT][256])  (round-11 proven) ====
template <int KTOT, bool RELU>
__global__ __launch_bounds__(512) void k_tile(const float* __restrict__ Amat, int lda,
                                              const float* __restrict__ Bmat,
                                              float* __restrict__ Cout) {
  __shared__ float As[2][32 * 32];   // 8 KB dbuf
  __shared__ float Bs[2][32 * 256];  // 64 KB dbuf
  const int i0 = blockIdx.x * 32;
  const int tid = threadIdx.x;
  const int rg = tid >> 7;
  const int ct = tid & 127;
  const int r0 = rg * 8;
  constexpr int NC = KTOT / 32;
  float acc[8][2] = {};

  if (tid < 256)
    gll16b(&Amat[(size_t)(i0 + (tid >> 3)) * lda + (tid & 7) * 4], &As[0][tid * 4]);
#pragma unroll
  for (int w = 0; w < 4; ++w) {
    const int lin = tid + 512 * w;
    gll16b(&Bmat[(size_t)(lin >> 6) * DE + (lin & 63) * 4], &Bs[0][lin * 4]);
  }

  for (int c = 0; c < NC; ++c) {
    __syncthreads();
    if (c + 1 < NC) {
      const int kb = (c + 1) * 32;
      if (tid < 256)
        gll16b(&Amat[(size_t)(i0 + (tid >> 3)) * lda + kb + (tid & 7) * 4],
               &As[(c + 1) & 1][tid * 4]);
#pragma unroll
      for (int w = 0; w < 4; ++w) {
        const int lin = tid + 512 * w;
        gll16b(&Bmat[(size_t)(kb + (lin >> 6)) * DE + (lin & 63) * 4],
               &Bs[(c + 1) & 1][lin * 4]);
      }
    }
    const float* as = &As[c & 1][0];
    const float* bs = &Bs[c & 1][0];
#pragma unroll 2
    for (int k4 = 0; k4 < 8; ++k4) {
      f4 a[8];
#pragma unroll
      for (int u = 0; u < 8; ++u)
        a[u] = *(const f4*)&as[(r0 + u) * 32 + k4 * 4];  // uniform bcast
#pragma unroll
      for (int kk = 0; kk < 4; ++kk) {  // k ascending
        float2 b = *(const float2*)&bs[(k4 * 4 + kk) * 256 + ct * 2];
#pragma unroll
        for (int u = 0; u < 8; ++u) {
          const float av = ((const float*)&a[u])[kk];
          acc[u][0] = __fmaf_rn(av, b.x, acc[u][0]);
          acc[u][1] = __fmaf_rn(av, b.y, acc[u][1]);
        }
      }
    }
  }
#pragma unroll
  for (int u = 0; u < 8; ++u) {
    float2 o;
    o.x = RELU ? fmaxf(acc[u][0], 0.0f) : acc[u][0];
    o.y = RELU ? fmaxf(acc[u][1], 0.0f) : acc[u][1];
    *(float2*)&Cout[(size_t)(i0 + r0 + u) * DE + ct * 2] = o;
  }
}

// ======== K3: sq (numpy-pairwise, exact) + hbbC bf16 chunked layout ========
// hbbC[kc][i][kk] = bf16(hb[i][kc*32+kk]), [8][8192][32] bf16.
__global__ __launch_bounds__(256) void k_sq32(const float* __restrict__ hb,
                                              float* __restrict__ sq,
                                              u16* __restrict__ hbbC) {
  const int row = blockIdx.x * 256 + threadIdx.x;
  const float* h = hb + (size_t)row * DE;
  float half[2];
#pragma unroll
  for (int hx = 0; hx < 2; ++hx) {
    float p[8] = {};
    for (int t = 0; t < 16; ++t) {
      const int k0 = hx * 128 + t * 8;
      f4 v0 = *(const f4*)&h[k0];
      f4 v1 = *(const f4*)&h[k0 + 4];
      const float* v0f = (const float*)&v0;
      const float* v1f = (const float*)&v1;
      short8v pk;
#pragma unroll
      for (int m = 0; m < 4; ++m) {
        p[m] = __fadd_rn(p[m], __fmul_rn(v0f[m], v0f[m]));
        p[4 + m] = __fadd_rn(p[4 + m], __fmul_rn(v1f[m], v1f[m]));
        pk[m] = (short)f2bf(v0f[m]);
        pk[4 + m] = (short)f2bf(v1f[m]);
      }
      *(short8v*)&hbbC[((size_t)(k0 >> 5) * NN + row) * 32 + (k0 & 31)] = pk;
    }
    const float t01 = __fadd_rn(p[0], p[1]), t23 = __fadd_rn(p[2], p[3]);
    const float t45 = __fadd_rn(p[4], p[5]), t67 = __fadd_rn(p[6], p[7]);
    half[hx] = __fadd_rn(__fadd_rn(t01, t23), __fadd_rn(t45, t67));
  }
  sq[row] = __fadd_rn(half[0], half[1]);
}

// ======== K4: bf16 MFMA screening + per-selector top-16 lists ========
// grid 256 x 512 thr (8 waves). Block = rows i0..i0+31, j-loop 32 tiles of 256.
// Wave wv covers 32 rows x 32 j (2x2 frags of 16x16x32). A-frags reg-resident.
// mfma_f32_16x16x32_bf16 layouts (m89): A lane l -> row l&15, k (l>>4)*8+e;
// B lane l -> col l&15, k (l>>4)*8+e; D lane l reg r -> row (l>>4)*4+r, col l&15.
__global__ __launch_bounds__(512) void k_scr(const u16* __restrict__ hbbC,
                                             const float* __restrict__ sqv,
                                             const float* __restrict__ q,
                                             const float* __restrict__ temp,
                                             float* __restrict__ wsV,
                                             int* __restrict__ wsJ) {
  __shared__ u16 Asb[8192];      // [8 kc][32 row][32 k] bf16, 16 KB
  __shared__ u16 Bsb[2][8192];   // [256 j][32 k] bf16 dbuf, 32 KB
  __shared__ float ssc[8192];    // [32 row][256 col] f32, 32 KB
  const int i0 = blockIdx.x * 32;
  const int tid = threadIdx.x;
  const int wv = tid >> 6;
  const int l = tid & 63;
  const int l4 = l >> 4, ll = l & 15;
  const int sr = tid >> 4, ss = tid & 15;

  // stage A (all 8 k-chunks) + B chunk 0
#pragma unroll
  for (int w2 = 0; w2 < 2; ++w2) {
    const int lin = tid + 512 * w2;
    gll16b(hbbC + ((size_t)(lin >> 7) * NN + i0) * 32 + (lin & 127) * 8,
           Asb + (size_t)lin * 8);
    gll16b(hbbC + (size_t)lin * 8, Bsb[0] + (size_t)lin * 8);
  }
  __syncthreads();  // drains gll

  short8v Areg[8][2];
#pragma unroll
  for (int kc = 0; kc < 8; ++kc)
#pragma unroll
    for (int rf = 0; rf < 2; ++rf)
      Areg[kc][rf] = *(const short8v*)&Asb[kc * 1024 + (rf * 16 + ll) * 32 + l4 * 8];

  const float tt = fminf(fmaxf(temp[0], -5.0f), 5.0f);
  const float C = expf(tt);
  float sqi[2][4];
#pragma unroll
  for (int rf = 0; rf < 2; ++rf)
#pragma unroll
    for (int r = 0; r < 4; ++r) sqi[rf][r] = sqv[i0 + rf * 16 + l4 * 4 + r];

  f32x4 acc[2][2] = {{{0.f, 0.f, 0.f, 0.f}, {0.f, 0.f, 0.f, 0.f}},
                     {{0.f, 0.f, 0.f, 0.f}, {0.f, 0.f, 0.f, 0.f}}};
  float lv[16];
  int lj[16];
#pragma unroll
  for (int u = 0; u < TK; ++u) { lv[u] = -3.0e38f; lj[u] = 0x7fffffff; }

  for (int cc = 0; cc < 256; ++cc) {  // jt = cc>>3, kc = cc&7
    __syncthreads();                  // Bsb[cc&1] staged
    if (cc + 1 < 256) {
      const int jt1 = (cc + 1) >> 3, kc1 = (cc + 1) & 7;
#pragma unroll
      for (int w2 = 0; w2 < 2; ++w2) {
        const int lin = tid + 512 * w2;
        gll16b(hbbC + (size_t)kc1 * (NN * 32) + (size_t)jt1 * 8192 + (size_t)lin * 8,
               Bsb[(cc + 1) & 1] + (size_t)lin * 8);
      }
    }
    const int kc = cc & 7;
    const u16* bs = Bsb[cc & 1];
#pragma unroll
    for (int cf = 0; cf < 2; ++cf) {
      short8v bfr = *(const short8v*)&bs[(wv * 32 + cf * 16 + ll) * 32 + l4 * 8];
#pragma unroll
      for (int rf = 0; rf < 2; ++rf)
        acc[rf][cf] = __builtin_amdgcn_mfma_f32_16x16x32_bf16(
            Areg[kc][rf], bfr, acc[rf][cf], 0, 0, 0);
    }
    if ((cc & 7) == 7) {
      const int jt = cc >> 3;
      // epilogue: score formula (screen precision) -> ssc
#pragma unroll
      for (int rf = 0; rf < 2; ++rf)
#pragma unroll
        for (int cf = 0; cf < 2; ++cf) {
          const int col = wv * 32 + cf * 16 + ll;
          const int j = jt * 256 + col;
          const float sqj = sqv[j];
#pragma unroll
          for (int r = 0; r < 4; ++r) {
            const int row = rf * 16 + l4 * 4 + r;
            float D = sqi[rf][r] + sqj - 2.0f * acc[rf][cf][r];
            D = fmaxf(D, 0.0f);
            const float qv = q[(size_t)(i0 + row) * NN + j];
            ssc[row * 256 + col] = logf(-logf(qv + 1e-8f)) - C * D;
            acc[rf][cf][r] = 0.0f;
          }
        }
      __syncthreads();  // ssc ready
      // selection: selector (sr, ss), j ascending -> strict > keeps lower j
      for (int c2 = 0; c2 < 16; ++c2) {
        const float v = ssc[sr * 256 + c2 * 16 + ss];
        if (v > lv[15]) {
          float cv = v;
          int cj = jt * 256 + c2 * 16 + ss;
#pragma unroll
          for (int u = 0; u < TK; ++u) {
            const bool take = (cv > lv[u]);
            const float nv2 = take ? cv : lv[u];
            const int nj2 = take ? cj : lj[u];
            cv = take ? lv[u] : cv;
            cj = take ? lj[u] : cj;
            lv[u] = nv2;
            lj[u] = nj2;
          }
        }
      }
    }
  }

  const size_t base = ((size_t)(i0 + sr) * 16 + ss) * (size_t)TK;
#pragma unroll
  for (int u = 0; u < TK; ++u) {
    wsV[base + u] = lv[u];
    wsJ[base + u] = lj[u];
  }
}

// ======== K5: per-row screen-t16 threshold -> compact candidate list ========
__global__ __launch_bounds__(64) void k_thr(const float* __restrict__ wsV,
                                            const int* __restrict__ wsJ,
                                            int* __restrict__ wsC,
                                            int* __restrict__ wsN) {
  const int r = blockIdx.x * 64 + threadIdx.x;
  const float* V = wsV + (size_t)r * 256;
  const int* J = wsJ + (size_t)r * 256;
  int cur[16];
#pragma unroll
  for (int u = 0; u < 16; ++u) cur[u] = 0;
  float t16 = -3.0e38f;
  for (int it = 0; it < TK; ++it) {  // 16-way merge of sorted lists
    float bv = -3.0e38f;
    int bj = 0x7fffffff, bl = 0;
    for (int u = 0; u < 16; ++u) {
      const int c = cur[u];
      if (c < TK) {
        const float v = V[u * TK + c];
        const int j = J[u * TK + c];
        if (v > bv || (v == bv && j < bj)) { bv = v; bj = j; bl = u; }
      }
    }
    cur[bl]++;
    t16 = bv;
  }
  const float tau = t16 - 0.02f;  // 10x the bf16 screen-error bound
  int cnt = 0;
  int* myc = wsC + (size_t)r * 32;
  for (int ci = 0; ci < 256; ++ci)
    if (V[ci] >= tau && cnt < 32) myc[cnt++] = J[ci];
  wsN[r] = cnt;
}

// ======== K6: exact canonical-f32 re-score of candidates ========
// Bitwise-identical chain to the round-11 accepted pipeline:
// k-ascending FMA dot + verbatim __f*_rn formula.
__global__ __launch_bounds__(256) void k_rfn(const int* __restrict__ wsC,
                                             const int* __restrict__ wsN,
                                             const float* __restrict__ hb,
                                             const float* __restrict__ sqv,
                                             const float* __restrict__ q,
                                             const float* __restrict__ temp,
                                             float* __restrict__ wsE) {
  const int gid = blockIdx.x * 256 + threadIdx.x;
  const int r = gid >> 5;
  const int slot = gid & 31;
  float s = -3.0e38f;
  if (slot < wsN[r]) {
    const int j = wsC[(size_t)r * 32 + slot];
    const float* hi = hb + (size_t)r * DE;
    const float* hj = hb + (size_t)j * DE;
    float d = 0.0f;
    for (int k4 = 0; k4 < 64; ++k4) {  // k ascending, canonical FMA chain
      f4 a = *(const f4*)&hi[k4 * 4];
      f4 b = *(const f4*)&hj[k4 * 4];
      d = __fmaf_rn(a.x, b.x, d);
      d = __fmaf_rn(a.y, b.y, d);
      d = __fmaf_rn(a.z, b.z, d);
      d = __fmaf_rn(a.w, b.w, d);
    }
    const float tt = fminf(fmaxf(temp[0], -5.0f), 5.0f);
    const float C = expf(tt);
    const float t1 = __fadd_rn(sqv[r], sqv[j]);
    float D = __fsub_rn(t1, __fmul_rn(2.0f, d));
    D = fmaxf(D, 0.0f);
    const float lg = __fmul_rn(D, C);
    const float p = __fadd_rn(q[(size_t)r * NN + j], 1e-8f);
    const float uu = logf(p);
    const float nv = logf(-uu);
    s = __fsub_rn(nv, lg);
  }
  wsE[(size_t)r * 32 + slot] = s;
}

// ======== K7: exact top-16 (value desc, index asc) per row ========
__global__ __launch_bounds__(64) void k_fin(const float* __restrict__ wsE,
                                            const int* __restrict__ wsC,
                                            const int* __restrict__ wsN,
                                            float* __restrict__ out) {
  const int r = blockIdx.x * 64 + threadIdx.x;
  const int cnt = wsN[r];
  float lv[16];
  int lj[16];
#pragma unroll
  for (int u = 0; u < TK; ++u) { lv[u] = -3.0e38f; lj[u] = 0x7fffffff; }
  for (int ci = 0; ci < cnt; ++ci) {
    const float v = wsE[(size_t)r * 32 + ci];
    const int j = wsC[(size_t)r * 32 + ci];
    if (v > lv[15] || (v == lv[15] && j < lj[15])) {
      float cv = v;
      int cj = j;
#pragma unroll
      for (int u = 0; u < TK; ++u) {
        const bool take = (cv > lv[u]) || (cv == lv[u] && cj < lj[u]);
        const float nv2 = take ? cv : lv[u];
        const int nj2 = take ? cj : lj[u];
        cv = take ? lv[u] : cv;
        cj = take ? lj[u] : cj;
        lv[u] = nv2;
        lj[u] = nj2;
      }
    }
  }
  float* E0 = out + (size_t)NN * DE;
  float* E1 = E0 + (size_t)NN * TK;
  float* LP = E1 + (size_t)NN * TK;
#pragma unroll
  for (int u = 0; u < TK; ++u) {
    E0[(size_t)r * TK + u] = (float)lj[u];
    E1[(size_t)r * TK + u] = (float)r;
    LP[(size_t)r * TK + u] = lv[u];
  }
}

extern "C" void kernel_launch(void* const* d_in, const int* in_sizes, int n_in,
                              void* d_out, int out_size, void* d_ws, size_t ws_size,
                              hipStream_t stream) {
  const float* x = (const float*)d_in[0];
  const float* A = (const float*)d_in[1];
  const float* W = (const float*)d_in[2];
  const float* temp = (const float*)d_in[3];
  const float* q = (const float*)d_in[4];
  float* out = (float*)d_out;

  char* ws = (char*)d_ws;
  float* xw   = (float*)(ws);             //  8,388,608 B
  float* sq   = (float*)(ws + 8388608);   //     32,768 B
  u16*   hbbC = (u16*)  (ws + 8421376);   //  4,194,304 B  [8][8192][32] bf16
  float* wsV  = (float*)(ws + 12615680);  //  8,388,608 B  [8192][16][16]
  int*   wsJ  = (int*)  (ws + 21004288);  //  8,388,608 B
  int*   wsC  = (int*)  (ws + 29392896);  //  1,048,576 B  [8192][32]
  int*   wsN  = (int*)  (ws + 30441472);  //     32,768 B
  float* wsE  = (float*)(ws + 30474240);  //  1,048,576 B  [8192][32]

  float* hb = out;  // [N, DE] f32 output region holds h

  hipLaunchKernelGGL((k_tile<DI, false>), dim3(NN / 32), dim3(512), 0, stream, x, DI, W, xw);
  hipLaunchKernelGGL((k_tile<NN, true>), dim3(NN / 32), dim3(512), 0, stream, A, NN, xw, hb);
  hipLaunchKernelGGL(k_sq32, dim3(NN / 256), dim3(256), 0, stream, hb, sq, hbbC);
  hipLaunchKernelGGL(k_scr, dim3(NN / 32), dim3(512), 0, stream, hbbC, sq, q, temp, wsV, wsJ);
  hipLaunchKernelGGL(k_thr, dim3(NN / 64), dim3(64), 0, stream, wsV, wsJ, wsC, wsN);
  hipLaunchKernelGGL(k_rfn, dim3(NN * 32 / 256), dim3(256), 0, stream, wsC, wsN, hb, sq, q, temp, wsE);
  hipLaunchKernelGGL(k_fin, dim3(NN / 64), dim3(64), 0, stream, wsE, wsC, wsN, out);
}